// Round 9
// baseline (425.849 us; speedup 1.0000x reference)
//
#include <hip/hip_runtime.h>
#include <hip/hip_bf16.h>
#include <cstdint>
#include <cstddef>

using bf16 = __hip_bfloat16;

typedef __attribute__((ext_vector_type(8))) short short8;
typedef __attribute__((ext_vector_type(4))) float floatx4;

constexpr int NLAYERS = 2;
constexpr int D_MODEL = 512;
constexpr int NHEAD   = 8;
constexpr int DH      = 64;
constexpr int SEQ     = 2048;
constexpr int BATCH   = 4;
constexpr int D_FF    = 2048;
constexpr int ROWS    = BATCH * SEQ;  // 8192

#define MODE_QKV     0
#define MODE_RELU    1
#define MODE_PARTIAL 2   // fp32 partial C (split-K), bias added by z==0 only

constexpr int BN = 128, BK = 64;

union S8 { short8 v; bf16 b[8]; ushort u[8]; };

__device__ inline ushort4 pack4_bf16(float4 v) {
    ushort4 u;
    u.x = __bfloat16_as_ushort(__float2bfloat16(v.x));
    u.y = __bfloat16_as_ushort(__float2bfloat16(v.y));
    u.z = __bfloat16_as_ushort(__float2bfloat16(v.z));
    u.w = __bfloat16_as_ushort(__float2bfloat16(v.w));
    return u;
}

__device__ inline void gld16(const void* g, void* l) {
    __builtin_amdgcn_global_load_lds(
        (const __attribute__((address_space(1))) void*)(uintptr_t)g,
        (__attribute__((address_space(3))) void*)(uint32_t)(uintptr_t)l,
        16, 0, 0);
}

// All five f32->bf16 conversions in one launch.
constexpr int CN1 = NLAYERS * 3 * D_MODEL * D_MODEL;  // qkv_w
constexpr int CN2 = NLAYERS * D_MODEL * D_MODEL;      // out_w
constexpr int CN3 = NLAYERS * D_FF * D_MODEL;         // w1
constexpr int CN4 = NLAYERS * D_MODEL * D_FF;         // w2
constexpr int CN5 = ROWS * D_MODEL;                   // src
constexpr int CNT = CN1 + CN2 + CN3 + CN4 + CN5;

__global__ __launch_bounds__(256) void cvt_all(
    const float* __restrict__ a1, const float* __restrict__ a2,
    const float* __restrict__ a3, const float* __restrict__ a4,
    const float* __restrict__ a5,
    bf16* __restrict__ d1, bf16* __restrict__ d2, bf16* __restrict__ d3,
    bf16* __restrict__ d4, bf16* __restrict__ d5)
{
    const int i = (blockIdx.x * 256 + threadIdx.x) * 4;
    const float* s; bf16* d; int off;
    if      (i < CN1)                   { s = a1; d = d1; off = i; }
    else if (i < CN1+CN2)               { s = a2; d = d2; off = i - CN1; }
    else if (i < CN1+CN2+CN3)           { s = a3; d = d3; off = i - (CN1+CN2); }
    else if (i < CN1+CN2+CN3+CN4)       { s = a4; d = d4; off = i - (CN1+CN2+CN3); }
    else if (i < CNT)                   { s = a5; d = d5; off = i - (CN1+CN2+CN3+CN4); }
    else return;
    *(ushort4*)(d + off) = pack4_bf16(*(const float4*)(s + off));
}

// C[M,N] = A[M,K] @ B[N,K]^T (+ bias).  R6/R8 verified 2-phase pipeline,
// LDS XOR-swizzle (linear gld16 dest + inverse-swizzled source + XOR'd read).
//   TBM=128: 4 waves 2x2, acc 4x4 (qkv / w1), whole K per block.
//   TBM=64 : 4 waves side-by-side, acc 4x2 (w2 / out-proj), SPLIT-K x2:
//            blockIdx.z selects K-half (Ksub = K/2); fp32 partials to
//            Pp[z*M*N + row*N + col]; bias added by z==0 only. Doubles the
//            grid (512 -> 1024 blocks, 3 blocks/CU by LDS) for TLP.
// Kfull is the row stride of A and B; Ksub the per-block K extent.
template<int TBM>
__global__ __launch_bounds__(256) void gemm_bt(
    const bf16* __restrict__ Ab,
    const bf16* __restrict__ Bw, const float* __restrict__ bias,
    bf16* __restrict__ Cb, float* __restrict__ Pp,
    bf16* __restrict__ Qo, bf16* __restrict__ Ko, bf16* __restrict__ Vo,
    int M, int N, int Kfull, int Ksub, int mode)
{
    constexpr int NJ = (TBM == 128) ? 4 : 2;
    __shared__ bf16 As[2][TBM][BK];
    __shared__ bf16 Bs[2][BN][BK];
    const int tid  = threadIdx.x;
    const int bn   = blockIdx.x * BN;
    const int bm   = blockIdx.y * TBM;
    const int z    = blockIdx.z;
    const int koff = z * Ksub;
    const int K    = Kfull;
    const int lane = tid & 63;
    const int wave = tid >> 6;
    const int wm   = (TBM == 128) ? (wave & 1) * 64 : 0;
    const int wn   = (TBM == 128) ? (wave >> 1) * 64 : wave * 32;

    floatx4 acc[4][NJ];
    #pragma unroll
    for (int i = 0; i < 4; i++)
        #pragma unroll
        for (int j = 0; j < NJ; j++)
            acc[i][j] = (floatx4){0.f, 0.f, 0.f, 0.f};

    const int l8  = lane >> 3;                 // row within 8-row group
    const int c8s = (((lane & 7) ^ l8) * 8);   // inverse-swizzled source chunk

    auto stage = [&](int buf, int k0) {
        #pragma unroll
        for (int c = 0; c < TBM / 32; ++c) {
            const int rowb = wave * (TBM / 4) + c * 8;
            gld16(Ab + (size_t)(bm + rowb + l8) * K + k0 + c8s, &As[buf][rowb][0]);
        }
        #pragma unroll
        for (int c = 0; c < 4; ++c) {
            const int rowb = wave * 32 + c * 8;
            gld16(Bw + (size_t)(bn + rowb + l8) * K + k0 + c8s, &Bs[buf][rowb][0]);
        }
    };

    const int nt = Ksub / BK;
    stage(0, koff);
    __syncthreads();
    int cur = 0;
    for (int t = 0; t < nt; ++t) {
        if (t + 1 < nt) stage(cur ^ 1, koff + (t + 1) * BK);   // prefetch
        #pragma unroll
        for (int ks = 0; ks < BK; ks += 32) {
            const int kk = ks + (lane >> 4) * 8;
            const int ri = lane & 15;
            const int csw = (((kk >> 3) ^ (ri & 7)) << 3);
            short8 af[4], bfr[NJ];
            #pragma unroll
            for (int i = 0; i < 4; i++) af[i]  = *(const short8*)&As[cur][wm + i*16 + ri][csw];
            #pragma unroll
            for (int j = 0; j < NJ; j++) bfr[j] = *(const short8*)&Bs[cur][wn + j*16 + ri][csw];
            #pragma unroll
            for (int i = 0; i < 4; i++)
                #pragma unroll
                for (int j = 0; j < NJ; j++)
                    acc[i][j] = __builtin_amdgcn_mfma_f32_16x16x32_bf16(af[i], bfr[j], acc[i][j], 0, 0, 0);
        }
        __syncthreads();   // drains prefetch vmcnt AFTER the MFMA covered it
        cur ^= 1;
    }

    const int cn = lane & 15;
    const int rb = (lane >> 4) * 4;
    #pragma unroll
    for (int j = 0; j < NJ; j++) {
        const int col = bn + wn + j * 16 + cn;
        const float bv = (mode == MODE_PARTIAL && z != 0) ? 0.f : bias[col];
        #pragma unroll
        for (int i = 0; i < 4; i++) {
            const int row0 = bm + wm + i * 16 + rb;
            if (mode == MODE_PARTIAL) {
                float* dst = Pp + (size_t)z * M * N;
                #pragma unroll
                for (int r = 0; r < 4; r++)
                    dst[(size_t)(row0 + r) * N + col] = acc[i][j][r] + bv;
            } else if (mode == MODE_RELU) {
                #pragma unroll
                for (int r = 0; r < 4; r++)
                    Cb[(size_t)(row0 + r) * N + col] =
                        __float2bfloat16(fmaxf(acc[i][j][r] + bv, 0.f));
            } else {  // MODE_QKV
                const int which = col >> 9;
                const int f = col & 511;
                const int h = f >> 6, d = f & 63;
                const int b = row0 >> 11, s = row0 & (SEQ - 1);
                if (which == 2) {
                    // V transposed: Vt[bh][d][s], 4 consecutive s -> 8B store
                    ushort4 u;
                    u.x = __bfloat16_as_ushort(__float2bfloat16(acc[i][j][0] + bv));
                    u.y = __bfloat16_as_ushort(__float2bfloat16(acc[i][j][1] + bv));
                    u.z = __bfloat16_as_ushort(__float2bfloat16(acc[i][j][2] + bv));
                    u.w = __bfloat16_as_ushort(__float2bfloat16(acc[i][j][3] + bv));
                    *(ushort4*)(Vo + ((size_t)(b * NHEAD + h) * DH + d) * SEQ + s) = u;
                } else {
                    bf16* dst = (which == 0) ? Qo : Ko;
                    #pragma unroll
                    for (int r = 0; r < 4; r++)
                        dst[(((size_t)b * NHEAD + h) * SEQ + s + r) * DH + d] =
                            __float2bfloat16(acc[i][j][r] + bv);
                }
            }
        }
    }
}

// MFMA attention, no K/V/Q staging (unchanged).
__global__ __launch_bounds__(256, 4) void attn_mfma(
    const bf16* __restrict__ Q, const bf16* __restrict__ K,
    const bf16* __restrict__ Vt, bf16* __restrict__ O)
{
    __shared__ float SL[16][148];    // stride 148 ≡ 20 banks: 2-way max
    __shared__ bf16  PL[16][168];    // stride 168*2B ≡ 20 banks: b128 conflict-free
    const int tid  = threadIdx.x;
    const int wave = tid >> 6;
    const int lane = tid & 63;
    const int gq0  = blockIdx.x * 16;
    const int s0   = gq0 & (SEQ - 1);
    const int bh   = gq0 >> 11;

    const bf16* Qb  = Q  + (size_t)bh * SEQ * DH;
    const bf16* Kb  = K  + (size_t)bh * SEQ * DH;
    const bf16* Vtb = Vt + (size_t)bh * DH * SEQ;

    // zero P pad (slots 144..159)
    PL[tid >> 4][144 + (tid & 15)] = __float2bfloat16(0.f);

    const int kk = (lane >> 4) * 8;
    const int ri = lane & 15;
    const int cn = lane & 15;
    const int rb = (lane >> 4) * 4;

    // --- S = Q.K^T * scale (9 key tiles over 4 waves, k=64 in 2 steps) ---
    {
        short8 a0 = *(const short8*)(Qb + (size_t)(s0 + ri) * DH + kk);
        short8 a1 = *(const short8*)(Qb + (size_t)(s0 + ri) * DH + kk + 32);
        for (int t = wave; t < 9; t += 4) {
            const int r = t * 16 + ri;
            int g;
            if (r < 80) g = s0 - 64 + r;
            else { const int e = r - 80; g = s0 + (e & 15) - (128 << (e >> 4)); }
            g = g < 0 ? 0 : g;     // clamped rows feed masked slots only
            const bf16* kr = Kb + (size_t)g * DH;
            short8 b0 = *(const short8*)(kr + kk);
            short8 b1 = *(const short8*)(kr + kk + 32);
            floatx4 acc = (floatx4){0.f, 0.f, 0.f, 0.f};
            acc = __builtin_amdgcn_mfma_f32_16x16x32_bf16(a0, b0, acc, 0, 0, 0);
            acc = __builtin_amdgcn_mfma_f32_16x16x32_bf16(a1, b1, acc, 0, 0, 0);
            #pragma unroll
            for (int r2 = 0; r2 < 4; r2++)
                SL[rb + r2][t * 16 + cn] = acc[r2] * 0.125f;
        }
    }
    __syncthreads();

    // --- masked softmax: wave handles queries 4w..4w+3 ---
    #pragma unroll
    for (int q4 = 0; q4 < 4; q4++) {
        const int q = wave * 4 + q4;
        const int s = s0 + q;
        float sc[3];
        bool  val[3];
        #pragma unroll
        for (int u = 0; u < 3; u++) {
            const int slot = lane + 64 * u;
            bool v = false;
            if (slot < 144) {
                if (slot < 80) {
                    const int g = s0 - 64 + slot;
                    v = (g >= 0) && (slot >= q) && (slot <= q + 64);
                } else {
                    const int e = slot - 80;
                    v = ((e & 15) == q) && (s - (128 << (e >> 4)) >= 0);
                }
            }
            val[u] = v;
            sc[u] = v ? SL[q][slot] : -1e30f;
        }
        float m = fmaxf(sc[0], fmaxf(sc[1], sc[2]));
        #pragma unroll
        for (int off = 32; off; off >>= 1) m = fmaxf(m, __shfl_xor(m, off, 64));
        float pv[3];
        float lsum = 0.f;
        #pragma unroll
        for (int u = 0; u < 3; u++) {
            pv[u] = val[u] ? __expf(fminf(sc[u] - m, 0.f)) : 0.f;
            lsum += pv[u];
        }
        #pragma unroll
        for (int off = 32; off; off >>= 1) lsum += __shfl_xor(lsum, off, 64);
        const float inv = 1.f / fmaxf(lsum, 1e-20f);
        #pragma unroll
        for (int u = 0; u < 3; u++) {
            const int slot = lane + 64 * u;
            if (slot < 144) PL[q][slot] = __float2bfloat16(pv[u] * inv);
        }
    }
    __syncthreads();

    // --- O = P.V^T (wave w -> dim tile w; k=160 in 5 steps) ---
    {
        const int d = wave * 16 + ri;
        const bf16* Vr = Vtb + (size_t)d * SEQ;
        short8 vb[5];
        #pragma unroll
        for (int u = 0; u < 5; u++) {
            const int slot = u * 32 + kk;
            if (slot >= 144) {
                vb[u] = (short8){0, 0, 0, 0, 0, 0, 0, 0};
            } else {
                int g0;
                if (slot < 80) g0 = s0 - 64 + slot;
                else { const int e = slot - 80; g0 = s0 + (e & 15) - (128 << (e >> 4)); }
                g0 = g0 < 0 ? 0 : g0;   // P is zero on masked slots
                vb[u] = *(const short8*)(Vr + g0);
            }
        }
        floatx4 acc = (floatx4){0.f, 0.f, 0.f, 0.f};
        #pragma unroll
        for (int u = 0; u < 5; u++) {
            short8 a = *(const short8*)&PL[ri][u * 32 + kk];
            acc = __builtin_amdgcn_mfma_f32_16x16x32_bf16(a, vb[u], acc, 0, 0, 0);
        }
        const int b = bh >> 3, h = bh & 7;
        #pragma unroll
        for (int r2 = 0; r2 < 4; r2++)
            O[((size_t)(b * SEQ + s0 + rb + r2)) * D_MODEL + h * DH + wave * 16 + cn]
                = __float2bfloat16(acc[r2]);
    }
}

// xout = LN(xin + p0 + p1) * gamma + beta. Wave-per-row, shuffle-only.
// p0/p1 are the fp32 split-K partials of the preceding GEMM (bias already
// in p0); fusing their sum here completes the split-K reduction for free.
__global__ __launch_bounds__(256) void ln_residual(
    const bf16* __restrict__ xin_b, const float* __restrict__ xin_f,
    const float* __restrict__ p0, const float* __restrict__ p1,
    const float* __restrict__ gamma, const float* __restrict__ beta,
    bf16* __restrict__ xout_b, float* __restrict__ xout_f)
{
    const int wave = threadIdx.x >> 6;
    const int lane = threadIdx.x & 63;
    const int row  = blockIdx.x * 4 + wave;
    const size_t base = (size_t)row * D_MODEL + lane * 8;

    float v[8];
    if (xin_f != nullptr) {
        float4 x0 = *(const float4*)(xin_f + base);
        float4 x1 = *(const float4*)(xin_f + base + 4);
        v[0] = x0.x; v[1] = x0.y; v[2] = x0.z; v[3] = x0.w;
        v[4] = x1.x; v[5] = x1.y; v[6] = x1.z; v[7] = x1.w;
    } else {
        S8 xb; xb.v = *(const short8*)(xin_b + base);
        #pragma unroll
        for (int j = 0; j < 8; j++) v[j] = __bfloat162float(xb.b[j]);
    }
    float4 pa0 = *(const float4*)(p0 + base);
    float4 pa1 = *(const float4*)(p0 + base + 4);
    float4 pb0 = *(const float4*)(p1 + base);
    float4 pb1 = *(const float4*)(p1 + base + 4);
    float p[8] = {pa0.x + pb0.x, pa0.y + pb0.y, pa0.z + pb0.z, pa0.w + pb0.w,
                  pa1.x + pb1.x, pa1.y + pb1.y, pa1.z + pb1.z, pa1.w + pb1.w};
    float sum = 0.f, sq = 0.f;
    #pragma unroll
    for (int j = 0; j < 8; j++) {
        v[j] += p[j];
        sum += v[j];
        sq  += v[j] * v[j];
    }
    #pragma unroll
    for (int off = 32; off; off >>= 1) {
        sum += __shfl_xor(sum, off, 64);
        sq  += __shfl_xor(sq,  off, 64);
    }
    const float mean = sum * (1.f / D_MODEL);
    const float var  = fmaxf(sq * (1.f / D_MODEL) - mean * mean, 0.f);
    const float r    = rsqrtf(var + 1e-5f);
    float4 g0 = *(const float4*)(gamma + lane * 8);
    float4 g1 = *(const float4*)(gamma + lane * 8 + 4);
    float4 b0 = *(const float4*)(beta  + lane * 8);
    float4 b1 = *(const float4*)(beta  + lane * 8 + 4);
    float g[8] = {g0.x, g0.y, g0.z, g0.w, g1.x, g1.y, g1.z, g1.w};
    float bb[8] = {b0.x, b0.y, b0.z, b0.w, b1.x, b1.y, b1.z, b1.w};
    float o[8];
    #pragma unroll
    for (int j = 0; j < 8; j++) o[j] = (v[j] - mean) * r * g[j] + bb[j];
    if (xout_f != nullptr) {
        *(float4*)(xout_f + base)     = (float4){o[0], o[1], o[2], o[3]};
        *(float4*)(xout_f + base + 4) = (float4){o[4], o[5], o[6], o[7]};
    } else {
        S8 ob;
        #pragma unroll
        for (int j = 0; j < 8; j++) ob.b[j] = __float2bfloat16(o[j]);
        *(short8*)(xout_b + base) = ob.v;
    }
}

extern "C" void kernel_launch(void* const* d_in, const int* in_sizes, int n_in,
                              void* d_out, int out_size, void* d_ws, size_t ws_size,
                              hipStream_t stream)
{
    const int want[12] = {1572864, 3072, 524288, 1024, 1024, 1024,
                          2097152, 4096, 2097152, 1024, 1024, 1024};
    int anchor = -1;
    for (int a = 2; a >= 1; --a) {
        if (n_in < a + 12) continue;
        bool ok = true;
        for (int i = 0; i < 12; i++) if (in_sizes[a + i] != want[i]) { ok = false; break; }
        if (ok) { anchor = a; break; }
    }
    if (anchor < 0) return;

    const float* src   = (const float*)d_in[0];
    const float* qkv_w = (const float*)d_in[anchor + 0];
    const float* qkv_b = (const float*)d_in[anchor + 1];
    const float* out_w = (const float*)d_in[anchor + 2];
    const float* out_b = (const float*)d_in[anchor + 3];
    const float* ln1_s = (const float*)d_in[anchor + 4];
    const float* ln1_b = (const float*)d_in[anchor + 5];
    const float* w1    = (const float*)d_in[anchor + 6];
    const float* b1    = (const float*)d_in[anchor + 7];
    const float* w2    = (const float*)d_in[anchor + 8];
    const float* b2    = (const float*)d_in[anchor + 9];
    const float* ln2_s = (const float*)d_in[anchor + 10];
    const float* ln2_b = (const float*)d_in[anchor + 11];
    float* out = (float*)d_out;

    constexpr size_t MiB = 1024 * 1024;
    if (ws_size < 104 * MiB) return;
    char* p = (char*)d_ws;
    bf16*  Q   = (bf16*)(p);                 //  0..8
    bf16*  Kt  = (bf16*)(p + 8 * MiB);       //  8..16
    bf16*  Vt  = (bf16*)(p + 16 * MiB);      // 16..24
    bf16*  O   = (bf16*)(p + 24 * MiB);      // 24..32
    bf16*  Hb  = (bf16*)(p);                 //  0..32 alias (Q/Kt/Vt/O dead by FFN)
    float* P01 = (float*)(p + 32 * MiB);     // 32..48: split-K partial z=0
    float* P   = P01;                        //   (z=1 at +16MiB inside kernel)
    bf16*  srcB= (bf16*)(p + 64 * MiB);      // 64..72 (lives cvt -> l0 QKV only)
    bf16*  xA  = (bf16*)(p + 72 * MiB);      // 72..80
    bf16*  qwB = (bf16*)(p + 80 * MiB);      // 3 MiB
    bf16*  owB = (bf16*)(p + 83 * MiB);      // 1 MiB
    bf16*  w1B = (bf16*)(p + 84 * MiB);      // 4 MiB
    bf16*  w2B = (bf16*)(p + 88 * MiB);      // 4 MiB -> ends 92 MiB
    float* P1  = P + (size_t)ROWS * D_MODEL; // z=1 partial view

    cvt_all<<<dim3(CNT / 4 / 256), 256, 0, stream>>>(
        qkv_w, out_w, w1, w2, src, qwB, owB, w1B, w2B, srcB);

    for (int l = 0; l < NLAYERS; ++l) {
        const bf16*  xin = (l == 0) ? srcB : xA;
        const float* xf  = (l == 0) ? src : nullptr;
        gemm_bt<128><<<dim3((3 * D_MODEL) / BN, ROWS / 128, 1), 256, 0, stream>>>(
            xin, qwB + (size_t)l * 3 * D_MODEL * D_MODEL, qkv_b + (size_t)l * 3 * D_MODEL,
            nullptr, nullptr, Q, Kt, Vt, ROWS, 3 * D_MODEL, D_MODEL, D_MODEL, MODE_QKV);
        attn_mfma<<<dim3(BATCH * NHEAD * SEQ / 16), 256, 0, stream>>>(Q, Kt, Vt, O);
        // out-proj: split-K x2 -> fp32 partials, reduced in ln_residual
        gemm_bt<64><<<dim3(D_MODEL / BN, ROWS / 64, 2), 256, 0, stream>>>(
            O, owB + (size_t)l * D_MODEL * D_MODEL, out_b + (size_t)l * D_MODEL,
            nullptr, P, nullptr, nullptr, nullptr,
            ROWS, D_MODEL, D_MODEL, D_MODEL / 2, MODE_PARTIAL);
        ln_residual<<<dim3(ROWS / 4), 256, 0, stream>>>(
            (l == 0) ? nullptr : xA, xf, P, P1,
            ln1_s + (size_t)l * D_MODEL, ln1_b + (size_t)l * D_MODEL,
            xA, nullptr);
        gemm_bt<128><<<dim3(D_FF / BN, ROWS / 128, 1), 256, 0, stream>>>(
            xA, w1B + (size_t)l * D_FF * D_MODEL, b1 + (size_t)l * D_FF,
            Hb, nullptr, nullptr, nullptr, nullptr,
            ROWS, D_FF, D_MODEL, D_MODEL, MODE_RELU);
        // w2: split-K x2 -> fp32 partials, reduced in ln_residual
        gemm_bt<64><<<dim3(D_MODEL / BN, ROWS / 64, 2), 256, 0, stream>>>(
            Hb, w2B + (size_t)l * D_MODEL * D_FF, b2 + (size_t)l * D_MODEL,
            nullptr, P, nullptr, nullptr, nullptr,
            ROWS, D_MODEL, D_FF, D_FF / 2, MODE_PARTIAL);
        if (l == NLAYERS - 1) {
            ln_residual<<<dim3(ROWS / 4), 256, 0, stream>>>(
                xA, nullptr, P, P1, ln2_s + (size_t)l * D_MODEL, ln2_b + (size_t)l * D_MODEL,
                nullptr, out);
        } else {
            ln_residual<<<dim3(ROWS / 4), 256, 0, stream>>>(
                xA, nullptr, P, P1, ln2_s + (size_t)l * D_MODEL, ln2_b + (size_t)l * D_MODEL,
                xA, nullptr);
        }
    }
}

// Round 10
// 377.103 us; speedup vs baseline: 1.1293x; 1.1293x over previous
//
#include <hip/hip_runtime.h>
#include <hip/hip_bf16.h>
#include <cstdint>
#include <cstddef>

using bf16 = __hip_bfloat16;

typedef __attribute__((ext_vector_type(8))) short short8;
typedef __attribute__((ext_vector_type(4))) float floatx4;

constexpr int NLAYERS = 2;
constexpr int D_MODEL = 512;
constexpr int NHEAD   = 8;
constexpr int DH      = 64;
constexpr int SEQ     = 2048;
constexpr int BATCH   = 4;
constexpr int D_FF    = 2048;
constexpr int ROWS    = BATCH * SEQ;  // 8192

#define MODE_QKV   0
#define MODE_RELU  1
#define MODE_PLAIN 2

constexpr int BN = 128, BK = 64;

union S8 { short8 v; bf16 b[8]; ushort u[8]; };

__device__ inline ushort4 pack4_bf16(float4 v) {
    ushort4 u;
    u.x = __bfloat16_as_ushort(__float2bfloat16(v.x));
    u.y = __bfloat16_as_ushort(__float2bfloat16(v.y));
    u.z = __bfloat16_as_ushort(__float2bfloat16(v.z));
    u.w = __bfloat16_as_ushort(__float2bfloat16(v.w));
    return u;
}

__device__ inline void gld16(const void* g, void* l) {
    __builtin_amdgcn_global_load_lds(
        (const __attribute__((address_space(1))) void*)(uintptr_t)g,
        (__attribute__((address_space(3))) void*)(uint32_t)(uintptr_t)l,
        16, 0, 0);
}

// All five f32->bf16 conversions in one launch.
constexpr int CN1 = NLAYERS * 3 * D_MODEL * D_MODEL;  // qkv_w
constexpr int CN2 = NLAYERS * D_MODEL * D_MODEL;      // out_w
constexpr int CN3 = NLAYERS * D_FF * D_MODEL;         // w1
constexpr int CN4 = NLAYERS * D_MODEL * D_FF;         // w2
constexpr int CN5 = ROWS * D_MODEL;                   // src
constexpr int CNT = CN1 + CN2 + CN3 + CN4 + CN5;

__global__ __launch_bounds__(256) void cvt_all(
    const float* __restrict__ a1, const float* __restrict__ a2,
    const float* __restrict__ a3, const float* __restrict__ a4,
    const float* __restrict__ a5,
    bf16* __restrict__ d1, bf16* __restrict__ d2, bf16* __restrict__ d3,
    bf16* __restrict__ d4, bf16* __restrict__ d5)
{
    const int i = (blockIdx.x * 256 + threadIdx.x) * 4;
    const float* s; bf16* d; int off;
    if      (i < CN1)                   { s = a1; d = d1; off = i; }
    else if (i < CN1+CN2)               { s = a2; d = d2; off = i - CN1; }
    else if (i < CN1+CN2+CN3)           { s = a3; d = d3; off = i - (CN1+CN2); }
    else if (i < CN1+CN2+CN3+CN4)       { s = a4; d = d4; off = i - (CN1+CN2+CN3); }
    else if (i < CNT)                   { s = a5; d = d5; off = i - (CN1+CN2+CN3+CN4); }
    else return;
    *(ushort4*)(d + off) = pack4_bf16(*(const float4*)(s + off));
}

// C[M,N] = A[M,K] @ B[N,K]^T + bias.  R8 verified config (best: 405.6us):
// 2-phase double-buffered pipeline, one barrier per K-step, LDS XOR-swizzle.
// NEW (R10): XCD-chunked blockIdx swizzle (T1). HW dispatches workgroups
// round-robin across the 8 XCDs by linear id, so consecutive ids (x-major,
// SAME A-panel) land on different L2s and each re-fetches A from HBM.
// Remap lin' = (hw%8)*(nwg/8) + hw/8: each XCD gets a contiguous chunk of
// x-rows -> A-panel fetched once per XCD-L2, sibling reads become L2 hits.
//   TBM=128: 4 waves 2x2, acc 4x4 (qkv / w1)
//   TBM=64 : 4 waves side-by-side, acc 4x2 (w2 / out-proj)
// MODE_QKV epilogue writes Q/K [b,h,s,d] and V directly transposed
// Vt[bh][d][s].
template<int TBM>
__global__ __launch_bounds__(256) void gemm_bt(
    const bf16* __restrict__ Ab,
    const bf16* __restrict__ Bw, const float* __restrict__ bias,
    bf16* __restrict__ Cb,
    bf16* __restrict__ Qo, bf16* __restrict__ Ko, bf16* __restrict__ Vo,
    int M, int N, int K, int mode)
{
    constexpr int NJ = (TBM == 128) ? 4 : 2;
    __shared__ bf16 As[2][TBM][BK];
    __shared__ bf16 Bs[2][BN][BK];
    const int tid  = threadIdx.x;

    // --- XCD-chunked swizzle (bijective; all grids here have nwg%8==0) ---
    const int gx  = gridDim.x;
    const int nwg = gx * gridDim.y;
    int lin = blockIdx.y * gx + blockIdx.x;
    if ((nwg & 7) == 0) {
        const int q = nwg >> 3;
        lin = (lin & 7) * q + (lin >> 3);
    }
    const int bn = (lin % gx) * BN;
    const int bm = (lin / gx) * TBM;

    const int lane = tid & 63;
    const int wave = tid >> 6;
    const int wm   = (TBM == 128) ? (wave & 1) * 64 : 0;
    const int wn   = (TBM == 128) ? (wave >> 1) * 64 : wave * 32;

    floatx4 acc[4][NJ];
    #pragma unroll
    for (int i = 0; i < 4; i++)
        #pragma unroll
        for (int j = 0; j < NJ; j++)
            acc[i][j] = (floatx4){0.f, 0.f, 0.f, 0.f};

    const int l8  = lane >> 3;                 // row within 8-row group
    const int c8s = (((lane & 7) ^ l8) * 8);   // inverse-swizzled source chunk

    auto stage = [&](int buf, int k0) {
        #pragma unroll
        for (int c = 0; c < TBM / 32; ++c) {
            const int rowb = wave * (TBM / 4) + c * 8;
            gld16(Ab + (size_t)(bm + rowb + l8) * K + k0 + c8s, &As[buf][rowb][0]);
        }
        #pragma unroll
        for (int c = 0; c < 4; ++c) {
            const int rowb = wave * 32 + c * 8;
            gld16(Bw + (size_t)(bn + rowb + l8) * K + k0 + c8s, &Bs[buf][rowb][0]);
        }
    };

    const int nt = K / BK;
    stage(0, 0);
    __syncthreads();
    int cur = 0;
    for (int t = 0; t < nt; ++t) {
        if (t + 1 < nt) stage(cur ^ 1, (t + 1) * BK);   // prefetch in flight
        #pragma unroll
        for (int ks = 0; ks < BK; ks += 32) {
            const int kk = ks + (lane >> 4) * 8;
            const int ri = lane & 15;
            const int csw = (((kk >> 3) ^ (ri & 7)) << 3);
            short8 af[4], bfr[NJ];
            #pragma unroll
            for (int i = 0; i < 4; i++) af[i]  = *(const short8*)&As[cur][wm + i*16 + ri][csw];
            #pragma unroll
            for (int j = 0; j < NJ; j++) bfr[j] = *(const short8*)&Bs[cur][wn + j*16 + ri][csw];
            #pragma unroll
            for (int i = 0; i < 4; i++)
                #pragma unroll
                for (int j = 0; j < NJ; j++)
                    acc[i][j] = __builtin_amdgcn_mfma_f32_16x16x32_bf16(af[i], bfr[j], acc[i][j], 0, 0, 0);
        }
        __syncthreads();   // drains prefetch vmcnt AFTER the MFMA covered it
        cur ^= 1;
    }

    const int cn = lane & 15;
    const int rb = (lane >> 4) * 4;
    #pragma unroll
    for (int j = 0; j < NJ; j++) {
        const int col = bn + wn + j * 16 + cn;
        const float bv = bias[col];
        #pragma unroll
        for (int i = 0; i < 4; i++) {
            const int row0 = bm + wm + i * 16 + rb;
            if (mode == MODE_RELU) {
                #pragma unroll
                for (int r = 0; r < 4; r++)
                    Cb[(size_t)(row0 + r) * N + col] =
                        __float2bfloat16(fmaxf(acc[i][j][r] + bv, 0.f));
            } else if (mode == MODE_PLAIN) {
                #pragma unroll
                for (int r = 0; r < 4; r++)
                    Cb[(size_t)(row0 + r) * N + col] =
                        __float2bfloat16(acc[i][j][r] + bv);
            } else {
                const int which = col >> 9;
                const int f = col & 511;
                const int h = f >> 6, d = f & 63;
                const int b = row0 >> 11, s = row0 & (SEQ - 1);
                if (which == 2) {
                    // V transposed: Vt[bh][d][s], 4 consecutive s -> 8B store
                    ushort4 u;
                    u.x = __bfloat16_as_ushort(__float2bfloat16(acc[i][j][0] + bv));
                    u.y = __bfloat16_as_ushort(__float2bfloat16(acc[i][j][1] + bv));
                    u.z = __bfloat16_as_ushort(__float2bfloat16(acc[i][j][2] + bv));
                    u.w = __bfloat16_as_ushort(__float2bfloat16(acc[i][j][3] + bv));
                    *(ushort4*)(Vo + ((size_t)(b * NHEAD + h) * DH + d) * SEQ + s) = u;
                } else {
                    bf16* dst = (which == 0) ? Qo : Ko;
                    #pragma unroll
                    for (int r = 0; r < 4; r++)
                        dst[(((size_t)b * NHEAD + h) * SEQ + s + r) * DH + d] =
                            __float2bfloat16(acc[i][j][r] + bv);
                }
            }
        }
    }
}

// MFMA attention, no K/V/Q staging (unchanged).
__global__ __launch_bounds__(256, 4) void attn_mfma(
    const bf16* __restrict__ Q, const bf16* __restrict__ K,
    const bf16* __restrict__ Vt, bf16* __restrict__ O)
{
    __shared__ float SL[16][148];    // stride 148 ≡ 20 banks: 2-way max
    __shared__ bf16  PL[16][168];    // stride 168*2B ≡ 20 banks: b128 conflict-free
    const int tid  = threadIdx.x;
    const int wave = tid >> 6;
    const int lane = tid & 63;
    const int gq0  = blockIdx.x * 16;
    const int s0   = gq0 & (SEQ - 1);
    const int bh   = gq0 >> 11;

    const bf16* Qb  = Q  + (size_t)bh * SEQ * DH;
    const bf16* Kb  = K  + (size_t)bh * SEQ * DH;
    const bf16* Vtb = Vt + (size_t)bh * DH * SEQ;

    // zero P pad (slots 144..159)
    PL[tid >> 4][144 + (tid & 15)] = __float2bfloat16(0.f);

    const int kk = (lane >> 4) * 8;
    const int ri = lane & 15;
    const int cn = lane & 15;
    const int rb = (lane >> 4) * 4;

    // --- S = Q.K^T * scale (9 key tiles over 4 waves, k=64 in 2 steps) ---
    {
        short8 a0 = *(const short8*)(Qb + (size_t)(s0 + ri) * DH + kk);
        short8 a1 = *(const short8*)(Qb + (size_t)(s0 + ri) * DH + kk + 32);
        for (int t = wave; t < 9; t += 4) {
            const int r = t * 16 + ri;
            int g;
            if (r < 80) g = s0 - 64 + r;
            else { const int e = r - 80; g = s0 + (e & 15) - (128 << (e >> 4)); }
            g = g < 0 ? 0 : g;     // clamped rows feed masked slots only
            const bf16* kr = Kb + (size_t)g * DH;
            short8 b0 = *(const short8*)(kr + kk);
            short8 b1 = *(const short8*)(kr + kk + 32);
            floatx4 acc = (floatx4){0.f, 0.f, 0.f, 0.f};
            acc = __builtin_amdgcn_mfma_f32_16x16x32_bf16(a0, b0, acc, 0, 0, 0);
            acc = __builtin_amdgcn_mfma_f32_16x16x32_bf16(a1, b1, acc, 0, 0, 0);
            #pragma unroll
            for (int r2 = 0; r2 < 4; r2++)
                SL[rb + r2][t * 16 + cn] = acc[r2] * 0.125f;
        }
    }
    __syncthreads();

    // --- masked softmax: wave handles queries 4w..4w+3 ---
    #pragma unroll
    for (int q4 = 0; q4 < 4; q4++) {
        const int q = wave * 4 + q4;
        const int s = s0 + q;
        float sc[3];
        bool  val[3];
        #pragma unroll
        for (int u = 0; u < 3; u++) {
            const int slot = lane + 64 * u;
            bool v = false;
            if (slot < 144) {
                if (slot < 80) {
                    const int g = s0 - 64 + slot;
                    v = (g >= 0) && (slot >= q) && (slot <= q + 64);
                } else {
                    const int e = slot - 80;
                    v = ((e & 15) == q) && (s - (128 << (e >> 4)) >= 0);
                }
            }
            val[u] = v;
            sc[u] = v ? SL[q][slot] : -1e30f;
        }
        float m = fmaxf(sc[0], fmaxf(sc[1], sc[2]));
        #pragma unroll
        for (int off = 32; off; off >>= 1) m = fmaxf(m, __shfl_xor(m, off, 64));
        float pv[3];
        float lsum = 0.f;
        #pragma unroll
        for (int u = 0; u < 3; u++) {
            pv[u] = val[u] ? __expf(fminf(sc[u] - m, 0.f)) : 0.f;
            lsum += pv[u];
        }
        #pragma unroll
        for (int off = 32; off; off >>= 1) lsum += __shfl_xor(lsum, off, 64);
        const float inv = 1.f / fmaxf(lsum, 1e-20f);
        #pragma unroll
        for (int u = 0; u < 3; u++) {
            const int slot = lane + 64 * u;
            if (slot < 144) PL[q][slot] = __float2bfloat16(pv[u] * inv);
        }
    }
    __syncthreads();

    // --- O = P.V^T (wave w -> dim tile w; k=160 in 5 steps) ---
    {
        const int d = wave * 16 + ri;
        const bf16* Vr = Vtb + (size_t)d * SEQ;
        short8 vb[5];
        #pragma unroll
        for (int u = 0; u < 5; u++) {
            const int slot = u * 32 + kk;
            if (slot >= 144) {
                vb[u] = (short8){0, 0, 0, 0, 0, 0, 0, 0};
            } else {
                int g0;
                if (slot < 80) g0 = s0 - 64 + slot;
                else { const int e = slot - 80; g0 = s0 + (e & 15) - (128 << (e >> 4)); }
                g0 = g0 < 0 ? 0 : g0;   // P is zero on masked slots
                vb[u] = *(const short8*)(Vr + g0);
            }
        }
        floatx4 acc = (floatx4){0.f, 0.f, 0.f, 0.f};
        #pragma unroll
        for (int u = 0; u < 5; u++) {
            short8 a = *(const short8*)&PL[ri][u * 32 + kk];
            acc = __builtin_amdgcn_mfma_f32_16x16x32_bf16(a, vb[u], acc, 0, 0, 0);
        }
        const int b = bh >> 3, h = bh & 7;
        #pragma unroll
        for (int r2 = 0; r2 < 4; r2++)
            O[((size_t)(b * SEQ + s0 + rb + r2)) * D_MODEL + h * DH + wave * 16 + cn]
                = __float2bfloat16(acc[r2]);
    }
}

// xout = LN(xin + t) * gamma + beta. Wave-per-row, shuffle-only, no barrier.
__global__ __launch_bounds__(256) void ln_residual(
    const bf16* __restrict__ xin_b, const float* __restrict__ xin_f,
    const bf16* __restrict__ t,
    const float* __restrict__ gamma, const float* __restrict__ beta,
    bf16* __restrict__ xout_b, float* __restrict__ xout_f)
{
    const int wave = threadIdx.x >> 6;
    const int lane = threadIdx.x & 63;
    const int row  = blockIdx.x * 4 + wave;
    const size_t base = (size_t)row * D_MODEL + lane * 8;

    float v[8];
    if (xin_f != nullptr) {
        float4 x0 = *(const float4*)(xin_f + base);
        float4 x1 = *(const float4*)(xin_f + base + 4);
        v[0] = x0.x; v[1] = x0.y; v[2] = x0.z; v[3] = x0.w;
        v[4] = x1.x; v[5] = x1.y; v[6] = x1.z; v[7] = x1.w;
    } else {
        S8 xb; xb.v = *(const short8*)(xin_b + base);
        #pragma unroll
        for (int j = 0; j < 8; j++) v[j] = __bfloat162float(xb.b[j]);
    }
    S8 tb; tb.v = *(const short8*)(t + base);
    float sum = 0.f, sq = 0.f;
    #pragma unroll
    for (int j = 0; j < 8; j++) {
        v[j] += __bfloat162float(tb.b[j]);
        sum += v[j];
        sq  += v[j] * v[j];
    }
    #pragma unroll
    for (int off = 32; off; off >>= 1) {
        sum += __shfl_xor(sum, off, 64);
        sq  += __shfl_xor(sq,  off, 64);
    }
    const float mean = sum * (1.f / D_MODEL);
    const float var  = fmaxf(sq * (1.f / D_MODEL) - mean * mean, 0.f);
    const float r    = rsqrtf(var + 1e-5f);
    float4 g0 = *(const float4*)(gamma + lane * 8);
    float4 g1 = *(const float4*)(gamma + lane * 8 + 4);
    float4 b0 = *(const float4*)(beta  + lane * 8);
    float4 b1 = *(const float4*)(beta  + lane * 8 + 4);
    float g[8] = {g0.x, g0.y, g0.z, g0.w, g1.x, g1.y, g1.z, g1.w};
    float bb[8] = {b0.x, b0.y, b0.z, b0.w, b1.x, b1.y, b1.z, b1.w};
    float o[8];
    #pragma unroll
    for (int j = 0; j < 8; j++) o[j] = (v[j] - mean) * r * g[j] + bb[j];
    if (xout_f != nullptr) {
        *(float4*)(xout_f + base)     = (float4){o[0], o[1], o[2], o[3]};
        *(float4*)(xout_f + base + 4) = (float4){o[4], o[5], o[6], o[7]};
    } else {
        S8 ob;
        #pragma unroll
        for (int j = 0; j < 8; j++) ob.b[j] = __float2bfloat16(o[j]);
        *(short8*)(xout_b + base) = ob.v;
    }
}

extern "C" void kernel_launch(void* const* d_in, const int* in_sizes, int n_in,
                              void* d_out, int out_size, void* d_ws, size_t ws_size,
                              hipStream_t stream)
{
    const int want[12] = {1572864, 3072, 524288, 1024, 1024, 1024,
                          2097152, 4096, 2097152, 1024, 1024, 1024};
    int anchor = -1;
    for (int a = 2; a >= 1; --a) {
        if (n_in < a + 12) continue;
        bool ok = true;
        for (int i = 0; i < 12; i++) if (in_sizes[a + i] != want[i]) { ok = false; break; }
        if (ok) { anchor = a; break; }
    }
    if (anchor < 0) return;

    const float* src   = (const float*)d_in[0];
    const float* qkv_w = (const float*)d_in[anchor + 0];
    const float* qkv_b = (const float*)d_in[anchor + 1];
    const float* out_w = (const float*)d_in[anchor + 2];
    const float* out_b = (const float*)d_in[anchor + 3];
    const float* ln1_s = (const float*)d_in[anchor + 4];
    const float* ln1_b = (const float*)d_in[anchor + 5];
    const float* w1    = (const float*)d_in[anchor + 6];
    const float* b1    = (const float*)d_in[anchor + 7];
    const float* w2    = (const float*)d_in[anchor + 8];
    const float* b2    = (const float*)d_in[anchor + 9];
    const float* ln2_s = (const float*)d_in[anchor + 10];
    const float* ln2_b = (const float*)d_in[anchor + 11];
    float* out = (float*)d_out;

    constexpr size_t MiB = 1024 * 1024;
    if (ws_size < 96 * MiB) return;
    char* p = (char*)d_ws;
    bf16*  Q   = (bf16*)(p);                 //  0..8
    bf16*  Kt  = (bf16*)(p + 8 * MiB);       //  8..16
    bf16*  Vt  = (bf16*)(p + 16 * MiB);      // 16..24
    bf16*  O   = (bf16*)(p + 24 * MiB);      // 24..32
    bf16*  Hb  = (bf16*)(p);                 //  0..32 alias (Q/Kt/Vt/O dead by FFN)
    bf16*  Tb  = (bf16*)(p + 32 * MiB);      // 32..40
    bf16*  srcB= (bf16*)(p + 40 * MiB);      // 40..48 (lives cvt -> l0 QKV only)
    bf16*  xA  = (bf16*)(p + 48 * MiB);      // 48..56
    bf16*  qwB = (bf16*)(p + 56 * MiB);      // 3 MiB
    bf16*  owB = (bf16*)(p + 59 * MiB);      // 1 MiB
    bf16*  w1B = (bf16*)(p + 60 * MiB);      // 4 MiB
    bf16*  w2B = (bf16*)(p + 64 * MiB);      // 4 MiB -> ends 68 MiB

    cvt_all<<<dim3(CNT / 4 / 256), 256, 0, stream>>>(
        qkv_w, out_w, w1, w2, src, qwB, owB, w1B, w2B, srcB);

    for (int l = 0; l < NLAYERS; ++l) {
        const bf16*  xin = (l == 0) ? srcB : xA;
        const float* xf  = (l == 0) ? src : nullptr;
        gemm_bt<128><<<dim3((3 * D_MODEL) / BN, ROWS / 128), 256, 0, stream>>>(
            xin, qwB + (size_t)l * 3 * D_MODEL * D_MODEL, qkv_b + (size_t)l * 3 * D_MODEL,
            nullptr, Q, Kt, Vt, ROWS, 3 * D_MODEL, D_MODEL, MODE_QKV);
        attn_mfma<<<dim3(BATCH * NHEAD * SEQ / 16), 256, 0, stream>>>(Q, Kt, Vt, O);
        gemm_bt<64><<<dim3(D_MODEL / BN, ROWS / 64), 256, 0, stream>>>(
            O, owB + (size_t)l * D_MODEL * D_MODEL, out_b + (size_t)l * D_MODEL,
            Tb, nullptr, nullptr, nullptr, ROWS, D_MODEL, D_MODEL, MODE_PLAIN);
        ln_residual<<<dim3(ROWS / 4), 256, 0, stream>>>(
            (l == 0) ? nullptr : xA, xf, Tb,
            ln1_s + (size_t)l * D_MODEL, ln1_b + (size_t)l * D_MODEL,
            xA, nullptr);
        gemm_bt<128><<<dim3(D_FF / BN, ROWS / 128), 256, 0, stream>>>(
            xA, w1B + (size_t)l * D_FF * D_MODEL, b1 + (size_t)l * D_FF,
            Hb, nullptr, nullptr, nullptr, ROWS, D_FF, D_MODEL, MODE_RELU);
        gemm_bt<64><<<dim3(D_MODEL / BN, ROWS / 64), 256, 0, stream>>>(
            Hb, w2B + (size_t)l * D_MODEL * D_FF, b2 + (size_t)l * D_MODEL,
            Tb, nullptr, nullptr, nullptr, ROWS, D_MODEL, D_FF, MODE_PLAIN);
        if (l == NLAYERS - 1) {
            ln_residual<<<dim3(ROWS / 4), 256, 0, stream>>>(
                xA, nullptr, Tb, ln2_s + (size_t)l * D_MODEL, ln2_b + (size_t)l * D_MODEL,
                nullptr, out);
        } else {
            ln_residual<<<dim3(ROWS / 4), 256, 0, stream>>>(
                xA, nullptr, Tb, ln2_s + (size_t)l * D_MODEL, ln2_b + (size_t)l * D_MODEL,
                xA, nullptr);
        }
    }
}

// Round 11
// 353.927 us; speedup vs baseline: 1.2032x; 1.0655x over previous
//
#include <hip/hip_runtime.h>
#include <hip/hip_bf16.h>
#include <cstdint>
#include <cstddef>

using bf16 = __hip_bfloat16;

typedef __attribute__((ext_vector_type(8))) short short8;
typedef __attribute__((ext_vector_type(4))) float floatx4;

constexpr int NLAYERS = 2;
constexpr int D_MODEL = 512;
constexpr int NHEAD   = 8;
constexpr int DH      = 64;
constexpr int SEQ     = 2048;
constexpr int BATCH   = 4;
constexpr int D_FF    = 2048;
constexpr int ROWS    = BATCH * SEQ;  // 8192

#define MODE_QKV   0
#define MODE_RELU  1
#define MODE_PLAIN 2

constexpr int BN = 128, BK = 64;

union S8 { short8 v; bf16 b[8]; ushort u[8]; };

__device__ inline ushort4 pack4_bf16(float4 v) {
    ushort4 u;
    u.x = __bfloat16_as_ushort(__float2bfloat16(v.x));
    u.y = __bfloat16_as_ushort(__float2bfloat16(v.y));
    u.z = __bfloat16_as_ushort(__float2bfloat16(v.z));
    u.w = __bfloat16_as_ushort(__float2bfloat16(v.w));
    return u;
}

__device__ inline void gld16(const void* g, void* l) {
    __builtin_amdgcn_global_load_lds(
        (const __attribute__((address_space(1))) void*)(uintptr_t)g,
        (__attribute__((address_space(3))) void*)(uint32_t)(uintptr_t)l,
        16, 0, 0);
}

// All five f32->bf16 conversions in one launch.
constexpr int CN1 = NLAYERS * 3 * D_MODEL * D_MODEL;  // qkv_w
constexpr int CN2 = NLAYERS * D_MODEL * D_MODEL;      // out_w
constexpr int CN3 = NLAYERS * D_FF * D_MODEL;         // w1
constexpr int CN4 = NLAYERS * D_MODEL * D_FF;         // w2
constexpr int CN5 = ROWS * D_MODEL;                   // src
constexpr int CNT = CN1 + CN2 + CN3 + CN4 + CN5;

__global__ __launch_bounds__(256) void cvt_all(
    const float* __restrict__ a1, const float* __restrict__ a2,
    const float* __restrict__ a3, const float* __restrict__ a4,
    const float* __restrict__ a5,
    bf16* __restrict__ d1, bf16* __restrict__ d2, bf16* __restrict__ d3,
    bf16* __restrict__ d4, bf16* __restrict__ d5)
{
    const int i = (blockIdx.x * 256 + threadIdx.x) * 4;
    const float* s; bf16* d; int off;
    if      (i < CN1)                   { s = a1; d = d1; off = i; }
    else if (i < CN1+CN2)               { s = a2; d = d2; off = i - CN1; }
    else if (i < CN1+CN2+CN3)           { s = a3; d = d3; off = i - (CN1+CN2); }
    else if (i < CN1+CN2+CN3+CN4)       { s = a4; d = d4; off = i - (CN1+CN2+CN3); }
    else if (i < CNT)                   { s = a5; d = d5; off = i - (CN1+CN2+CN3+CN4); }
    else return;
    *(ushort4*)(d + off) = pack4_bf16(*(const float4*)(s + off));
}

// Shared epilogue for both GEMM kernels.
template<int TBM, int NJ>
__device__ inline void gemm_epilogue(
    floatx4 (&acc)[4][NJ], const float* bias,
    bf16* Cb, bf16* Qo, bf16* Ko, bf16* Vo,
    int bm, int bn, int wm, int wn, int lane, int N, int mode)
{
    const int cn = lane & 15;
    const int rb = (lane >> 4) * 4;
    #pragma unroll
    for (int j = 0; j < NJ; j++) {
        const int col = bn + wn + j * 16 + cn;
        const float bv = bias[col];
        #pragma unroll
        for (int i = 0; i < 4; i++) {
            const int row0 = bm + wm + i * 16 + rb;
            if (mode == MODE_RELU) {
                #pragma unroll
                for (int r = 0; r < 4; r++)
                    Cb[(size_t)(row0 + r) * N + col] =
                        __float2bfloat16(fmaxf(acc[i][j][r] + bv, 0.f));
            } else if (mode == MODE_PLAIN) {
                #pragma unroll
                for (int r = 0; r < 4; r++)
                    Cb[(size_t)(row0 + r) * N + col] =
                        __float2bfloat16(acc[i][j][r] + bv);
            } else {
                const int which = col >> 9;
                const int f = col & 511;
                const int h = f >> 6, d = f & 63;
                const int b = row0 >> 11, s = row0 & (SEQ - 1);
                if (which == 2) {
                    // V transposed: Vt[bh][d][s], 4 consecutive s -> 8B store
                    ushort4 u;
                    u.x = __bfloat16_as_ushort(__float2bfloat16(acc[i][j][0] + bv));
                    u.y = __bfloat16_as_ushort(__float2bfloat16(acc[i][j][1] + bv));
                    u.z = __bfloat16_as_ushort(__float2bfloat16(acc[i][j][2] + bv));
                    u.w = __bfloat16_as_ushort(__float2bfloat16(acc[i][j][3] + bv));
                    *(ushort4*)(Vo + ((size_t)(b * NHEAD + h) * DH + d) * SEQ + s) = u;
                } else {
                    bf16* dst = (which == 0) ? Qo : Ko;
                    #pragma unroll
                    for (int r = 0; r < 4; r++)
                        dst[(((size_t)b * NHEAD + h) * SEQ + s + r) * DH + d] =
                            __float2bfloat16(acc[i][j][r] + bv);
                }
            }
        }
    }
}

// TBM=128 GEMM (qkv / w1): R10 verified config — 2-phase double-buffered
// pipeline, one barrier per K-step, LDS XOR-swizzle, XCD-chunked blockIdx
// swizzle. Unchanged.
__global__ __launch_bounds__(256) void gemm_bt128(
    const bf16* __restrict__ Ab,
    const bf16* __restrict__ Bw, const float* __restrict__ bias,
    bf16* __restrict__ Cb,
    bf16* __restrict__ Qo, bf16* __restrict__ Ko, bf16* __restrict__ Vo,
    int M, int N, int K, int mode)
{
    constexpr int TBM = 128, NJ = 4;
    __shared__ bf16 As[2][TBM][BK];
    __shared__ bf16 Bs[2][BN][BK];
    const int tid  = threadIdx.x;

    const int gx  = gridDim.x;
    const int nwg = gx * gridDim.y;
    int lin = blockIdx.y * gx + blockIdx.x;
    if ((nwg & 7) == 0) {
        const int q = nwg >> 3;
        lin = (lin & 7) * q + (lin >> 3);
    }
    const int bn = (lin % gx) * BN;
    const int bm = (lin / gx) * TBM;

    const int lane = tid & 63;
    const int wave = tid >> 6;
    const int wm   = (wave & 1) * 64;
    const int wn   = (wave >> 1) * 64;

    floatx4 acc[4][NJ];
    #pragma unroll
    for (int i = 0; i < 4; i++)
        #pragma unroll
        for (int j = 0; j < NJ; j++)
            acc[i][j] = (floatx4){0.f, 0.f, 0.f, 0.f};

    const int l8  = lane >> 3;
    const int c8s = (((lane & 7) ^ l8) * 8);

    auto stage = [&](int buf, int k0) {
        #pragma unroll
        for (int c = 0; c < 4; ++c) {
            const int rowb = wave * 32 + c * 8;
            gld16(Ab + (size_t)(bm + rowb + l8) * K + k0 + c8s, &As[buf][rowb][0]);
            gld16(Bw + (size_t)(bn + rowb + l8) * K + k0 + c8s, &Bs[buf][rowb][0]);
        }
    };

    const int nt = K / BK;
    stage(0, 0);
    __syncthreads();
    int cur = 0;
    for (int t = 0; t < nt; ++t) {
        if (t + 1 < nt) stage(cur ^ 1, (t + 1) * BK);
        #pragma unroll
        for (int ks = 0; ks < BK; ks += 32) {
            const int kk = ks + (lane >> 4) * 8;
            const int ri = lane & 15;
            const int csw = (((kk >> 3) ^ (ri & 7)) << 3);
            short8 af[4], bfr[NJ];
            #pragma unroll
            for (int i = 0; i < 4; i++) af[i]  = *(const short8*)&As[cur][wm + i*16 + ri][csw];
            #pragma unroll
            for (int j = 0; j < NJ; j++) bfr[j] = *(const short8*)&Bs[cur][wn + j*16 + ri][csw];
            #pragma unroll
            for (int i = 0; i < 4; i++)
                #pragma unroll
                for (int j = 0; j < NJ; j++)
                    acc[i][j] = __builtin_amdgcn_mfma_f32_16x16x32_bf16(af[i], bfr[j], acc[i][j], 0, 0, 0);
        }
        __syncthreads();
        cur ^= 1;
    }
    gemm_epilogue<TBM, NJ>(acc, bias, Cb, Qo, Ko, Vo, bm, bn, wm, wn, lane, N, mode);
}

// TBM=64 GEMM (w2 / out-proj): NEW — depth-2 counted-vmcnt pipeline (T4,
// R7 structure now ISOLATED from the TBM=128 regression that confounded it).
// 3 LDS buffers, 2 tiles in flight; per iter: vmcnt(6) waits only tile t's
// 6 loads (t+1's stay in flight across the barrier); stage(t+2) issued
// before the MFMA phase; vmcnt(0) only in the tail. Buffer (t+2)%3 was last
// read at iter t-1, complete for all waves before the barrier just crossed.
__global__ __launch_bounds__(256) void gemm_bt64(
    const bf16* __restrict__ Ab,
    const bf16* __restrict__ Bw, const float* __restrict__ bias,
    bf16* __restrict__ Cb,
    int M, int N, int K, int mode)
{
    constexpr int TBM = 64, NJ = 2;
    __shared__ bf16 As[3][TBM][BK];
    __shared__ bf16 Bs[3][BN][BK];
    const int tid  = threadIdx.x;

    const int gx  = gridDim.x;
    const int nwg = gx * gridDim.y;
    int lin = blockIdx.y * gx + blockIdx.x;
    if ((nwg & 7) == 0) {
        const int q = nwg >> 3;
        lin = (lin & 7) * q + (lin >> 3);
    }
    const int bn = (lin % gx) * BN;
    const int bm = (lin / gx) * TBM;

    const int lane = tid & 63;
    const int wave = tid >> 6;
    const int wn   = wave * 32;

    floatx4 acc[4][NJ];
    #pragma unroll
    for (int i = 0; i < 4; i++)
        #pragma unroll
        for (int j = 0; j < NJ; j++)
            acc[i][j] = (floatx4){0.f, 0.f, 0.f, 0.f};

    const int l8  = lane >> 3;
    const int c8s = (((lane & 7) ^ l8) * 8);

    auto stage = [&](int buf, int k0) {
        #pragma unroll
        for (int c = 0; c < 2; ++c) {
            const int rowb = wave * 16 + c * 8;
            gld16(Ab + (size_t)(bm + rowb + l8) * K + k0 + c8s, &As[buf][rowb][0]);
        }
        #pragma unroll
        for (int c = 0; c < 4; ++c) {
            const int rowb = wave * 32 + c * 8;
            gld16(Bw + (size_t)(bn + rowb + l8) * K + k0 + c8s, &Bs[buf][rowb][0]);
        }
    };

    const int nt = K / BK;      // 8 (out-proj) or 32 (w2)
    stage(0, 0);
    stage(1, BK);
    int cur = 0;
    for (int t = 0; t < nt; ++t) {
        if (t + 1 < nt) {
            asm volatile("s_waitcnt vmcnt(6)" ::: "memory");
        } else {
            asm volatile("s_waitcnt vmcnt(0)" ::: "memory");
        }
        __builtin_amdgcn_s_barrier();
        __builtin_amdgcn_sched_barrier(0);
        if (t + 2 < nt) {
            int nb = cur + 2; if (nb >= 3) nb -= 3;
            stage(nb, (t + 2) * BK);
        }
        #pragma unroll
        for (int ks = 0; ks < BK; ks += 32) {
            const int kk = ks + (lane >> 4) * 8;
            const int ri = lane & 15;
            const int csw = (((kk >> 3) ^ (ri & 7)) << 3);
            short8 af[4], bfr[NJ];
            #pragma unroll
            for (int i = 0; i < 4; i++) af[i]  = *(const short8*)&As[cur][i*16 + ri][csw];
            #pragma unroll
            for (int j = 0; j < NJ; j++) bfr[j] = *(const short8*)&Bs[cur][wn + j*16 + ri][csw];
            #pragma unroll
            for (int i = 0; i < 4; i++)
                #pragma unroll
                for (int j = 0; j < NJ; j++)
                    acc[i][j] = __builtin_amdgcn_mfma_f32_16x16x32_bf16(af[i], bfr[j], acc[i][j], 0, 0, 0);
        }
        cur = cur + 1; if (cur >= 3) cur = 0;
    }
    gemm_epilogue<TBM, NJ>(acc, bias, Cb, nullptr, nullptr, nullptr,
                           bm, bn, 0, wn, lane, N, mode);
}

// MFMA attention, no K/V/Q staging (unchanged).
__global__ __launch_bounds__(256, 4) void attn_mfma(
    const bf16* __restrict__ Q, const bf16* __restrict__ K,
    const bf16* __restrict__ Vt, bf16* __restrict__ O)
{
    __shared__ float SL[16][148];    // stride 148 ≡ 20 banks: 2-way max
    __shared__ bf16  PL[16][168];    // stride 168*2B ≡ 20 banks: b128 conflict-free
    const int tid  = threadIdx.x;
    const int wave = tid >> 6;
    const int lane = tid & 63;
    const int gq0  = blockIdx.x * 16;
    const int s0   = gq0 & (SEQ - 1);
    const int bh   = gq0 >> 11;

    const bf16* Qb  = Q  + (size_t)bh * SEQ * DH;
    const bf16* Kb  = K  + (size_t)bh * SEQ * DH;
    const bf16* Vtb = Vt + (size_t)bh * DH * SEQ;

    // zero P pad (slots 144..159)
    PL[tid >> 4][144 + (tid & 15)] = __float2bfloat16(0.f);

    const int kk = (lane >> 4) * 8;
    const int ri = lane & 15;
    const int cn = lane & 15;
    const int rb = (lane >> 4) * 4;

    // --- S = Q.K^T * scale (9 key tiles over 4 waves, k=64 in 2 steps) ---
    {
        short8 a0 = *(const short8*)(Qb + (size_t)(s0 + ri) * DH + kk);
        short8 a1 = *(const short8*)(Qb + (size_t)(s0 + ri) * DH + kk + 32);
        for (int t = wave; t < 9; t += 4) {
            const int r = t * 16 + ri;
            int g;
            if (r < 80) g = s0 - 64 + r;
            else { const int e = r - 80; g = s0 + (e & 15) - (128 << (e >> 4)); }
            g = g < 0 ? 0 : g;     // clamped rows feed masked slots only
            const bf16* kr = Kb + (size_t)g * DH;
            short8 b0 = *(const short8*)(kr + kk);
            short8 b1 = *(const short8*)(kr + kk + 32);
            floatx4 acc = (floatx4){0.f, 0.f, 0.f, 0.f};
            acc = __builtin_amdgcn_mfma_f32_16x16x32_bf16(a0, b0, acc, 0, 0, 0);
            acc = __builtin_amdgcn_mfma_f32_16x16x32_bf16(a1, b1, acc, 0, 0, 0);
            #pragma unroll
            for (int r2 = 0; r2 < 4; r2++)
                SL[rb + r2][t * 16 + cn] = acc[r2] * 0.125f;
        }
    }
    __syncthreads();

    // --- masked softmax: wave handles queries 4w..4w+3 ---
    #pragma unroll
    for (int q4 = 0; q4 < 4; q4++) {
        const int q = wave * 4 + q4;
        const int s = s0 + q;
        float sc[3];
        bool  val[3];
        #pragma unroll
        for (int u = 0; u < 3; u++) {
            const int slot = lane + 64 * u;
            bool v = false;
            if (slot < 144) {
                if (slot < 80) {
                    const int g = s0 - 64 + slot;
                    v = (g >= 0) && (slot >= q) && (slot <= q + 64);
                } else {
                    const int e = slot - 80;
                    v = ((e & 15) == q) && (s - (128 << (e >> 4)) >= 0);
                }
            }
            val[u] = v;
            sc[u] = v ? SL[q][slot] : -1e30f;
        }
        float m = fmaxf(sc[0], fmaxf(sc[1], sc[2]));
        #pragma unroll
        for (int off = 32; off; off >>= 1) m = fmaxf(m, __shfl_xor(m, off, 64));
        float pv[3];
        float lsum = 0.f;
        #pragma unroll
        for (int u = 0; u < 3; u++) {
            pv[u] = val[u] ? __expf(fminf(sc[u] - m, 0.f)) : 0.f;
            lsum += pv[u];
        }
        #pragma unroll
        for (int off = 32; off; off >>= 1) lsum += __shfl_xor(lsum, off, 64);
        const float inv = 1.f / fmaxf(lsum, 1e-20f);
        #pragma unroll
        for (int u = 0; u < 3; u++) {
            const int slot = lane + 64 * u;
            if (slot < 144) PL[q][slot] = __float2bfloat16(pv[u] * inv);
        }
    }
    __syncthreads();

    // --- O = P.V^T (wave w -> dim tile w; k=160 in 5 steps) ---
    {
        const int d = wave * 16 + ri;
        const bf16* Vr = Vtb + (size_t)d * SEQ;
        short8 vb[5];
        #pragma unroll
        for (int u = 0; u < 5; u++) {
            const int slot = u * 32 + kk;
            if (slot >= 144) {
                vb[u] = (short8){0, 0, 0, 0, 0, 0, 0, 0};
            } else {
                int g0;
                if (slot < 80) g0 = s0 - 64 + slot;
                else { const int e = slot - 80; g0 = s0 + (e & 15) - (128 << (e >> 4)); }
                g0 = g0 < 0 ? 0 : g0;   // P is zero on masked slots
                vb[u] = *(const short8*)(Vr + g0);
            }
        }
        floatx4 acc = (floatx4){0.f, 0.f, 0.f, 0.f};
        #pragma unroll
        for (int u = 0; u < 5; u++) {
            short8 a = *(const short8*)&PL[ri][u * 32 + kk];
            acc = __builtin_amdgcn_mfma_f32_16x16x32_bf16(a, vb[u], acc, 0, 0, 0);
        }
        const int b = bh >> 3, h = bh & 7;
        #pragma unroll
        for (int r2 = 0; r2 < 4; r2++)
            O[((size_t)(b * SEQ + s0 + rb + r2)) * D_MODEL + h * DH + wave * 16 + cn]
                = __float2bfloat16(acc[r2]);
    }
}

// xout = LN(xin + t) * gamma + beta. Wave-per-row, shuffle-only, no barrier.
__global__ __launch_bounds__(256) void ln_residual(
    const bf16* __restrict__ xin_b, const float* __restrict__ xin_f,
    const bf16* __restrict__ t,
    const float* __restrict__ gamma, const float* __restrict__ beta,
    bf16* __restrict__ xout_b, float* __restrict__ xout_f)
{
    const int wave = threadIdx.x >> 6;
    const int lane = threadIdx.x & 63;
    const int row  = blockIdx.x * 4 + wave;
    const size_t base = (size_t)row * D_MODEL + lane * 8;

    float v[8];
    if (xin_f != nullptr) {
        float4 x0 = *(const float4*)(xin_f + base);
        float4 x1 = *(const float4*)(xin_f + base + 4);
        v[0] = x0.x; v[1] = x0.y; v[2] = x0.z; v[3] = x0.w;
        v[4] = x1.x; v[5] = x1.y; v[6] = x1.z; v[7] = x1.w;
    } else {
        S8 xb; xb.v = *(const short8*)(xin_b + base);
        #pragma unroll
        for (int j = 0; j < 8; j++) v[j] = __bfloat162float(xb.b[j]);
    }
    S8 tb; tb.v = *(const short8*)(t + base);
    float sum = 0.f, sq = 0.f;
    #pragma unroll
    for (int j = 0; j < 8; j++) {
        v[j] += __bfloat162float(tb.b[j]);
        sum += v[j];
        sq  += v[j] * v[j];
    }
    #pragma unroll
    for (int off = 32; off; off >>= 1) {
        sum += __shfl_xor(sum, off, 64);
        sq  += __shfl_xor(sq,  off, 64);
    }
    const float mean = sum * (1.f / D_MODEL);
    const float var  = fmaxf(sq * (1.f / D_MODEL) - mean * mean, 0.f);
    const float r    = rsqrtf(var + 1e-5f);
    float4 g0 = *(const float4*)(gamma + lane * 8);
    float4 g1 = *(const float4*)(gamma + lane * 8 + 4);
    float4 b0 = *(const float4*)(beta  + lane * 8);
    float4 b1 = *(const float4*)(beta  + lane * 8 + 4);
    float g[8] = {g0.x, g0.y, g0.z, g0.w, g1.x, g1.y, g1.z, g1.w};
    float bb[8] = {b0.x, b0.y, b0.z, b0.w, b1.x, b1.y, b1.z, b1.w};
    float o[8];
    #pragma unroll
    for (int j = 0; j < 8; j++) o[j] = (v[j] - mean) * r * g[j] + bb[j];
    if (xout_f != nullptr) {
        *(float4*)(xout_f + base)     = (float4){o[0], o[1], o[2], o[3]};
        *(float4*)(xout_f + base + 4) = (float4){o[4], o[5], o[6], o[7]};
    } else {
        S8 ob;
        #pragma unroll
        for (int j = 0; j < 8; j++) ob.b[j] = __float2bfloat16(o[j]);
        *(short8*)(xout_b + base) = ob.v;
    }
}

extern "C" void kernel_launch(void* const* d_in, const int* in_sizes, int n_in,
                              void* d_out, int out_size, void* d_ws, size_t ws_size,
                              hipStream_t stream)
{
    const int want[12] = {1572864, 3072, 524288, 1024, 1024, 1024,
                          2097152, 4096, 2097152, 1024, 1024, 1024};
    int anchor = -1;
    for (int a = 2; a >= 1; --a) {
        if (n_in < a + 12) continue;
        bool ok = true;
        for (int i = 0; i < 12; i++) if (in_sizes[a + i] != want[i]) { ok = false; break; }
        if (ok) { anchor = a; break; }
    }
    if (anchor < 0) return;

    const float* src   = (const float*)d_in[0];
    const float* qkv_w = (const float*)d_in[anchor + 0];
    const float* qkv_b = (const float*)d_in[anchor + 1];
    const float* out_w = (const float*)d_in[anchor + 2];
    const float* out_b = (const float*)d_in[anchor + 3];
    const float* ln1_s = (const float*)d_in[anchor + 4];
    const float* ln1_b = (const float*)d_in[anchor + 5];
    const float* w1    = (const float*)d_in[anchor + 6];
    const float* b1    = (const float*)d_in[anchor + 7];
    const float* w2    = (const float*)d_in[anchor + 8];
    const float* b2    = (const float*)d_in[anchor + 9];
    const float* ln2_s = (const float*)d_in[anchor + 10];
    const float* ln2_b = (const float*)d_in[anchor + 11];
    float* out = (float*)d_out;

    constexpr size_t MiB = 1024 * 1024;
    if (ws_size < 96 * MiB) return;
    char* p = (char*)d_ws;
    bf16*  Q   = (bf16*)(p);                 //  0..8
    bf16*  Kt  = (bf16*)(p + 8 * MiB);       //  8..16
    bf16*  Vt  = (bf16*)(p + 16 * MiB);      // 16..24
    bf16*  O   = (bf16*)(p + 24 * MiB);      // 24..32
    bf16*  Hb  = (bf16*)(p);                 //  0..32 alias (Q/Kt/Vt/O dead by FFN)
    bf16*  Tb  = (bf16*)(p + 32 * MiB);      // 32..40
    bf16*  srcB= (bf16*)(p + 40 * MiB);      // 40..48 (lives cvt -> l0 QKV only)
    bf16*  xA  = (bf16*)(p + 48 * MiB);      // 48..56
    bf16*  qwB = (bf16*)(p + 56 * MiB);      // 3 MiB
    bf16*  owB = (bf16*)(p + 59 * MiB);      // 1 MiB
    bf16*  w1B = (bf16*)(p + 60 * MiB);      // 4 MiB
    bf16*  w2B = (bf16*)(p + 64 * MiB);      // 4 MiB -> ends 68 MiB

    cvt_all<<<dim3(CNT / 4 / 256), 256, 0, stream>>>(
        qkv_w, out_w, w1, w2, src, qwB, owB, w1B, w2B, srcB);

    for (int l = 0; l < NLAYERS; ++l) {
        const bf16*  xin = (l == 0) ? srcB : xA;
        const float* xf  = (l == 0) ? src : nullptr;
        gemm_bt128<<<dim3((3 * D_MODEL) / BN, ROWS / 128), 256, 0, stream>>>(
            xin, qwB + (size_t)l * 3 * D_MODEL * D_MODEL, qkv_b + (size_t)l * 3 * D_MODEL,
            nullptr, Q, Kt, Vt, ROWS, 3 * D_MODEL, D_MODEL, MODE_QKV);
        attn_mfma<<<dim3(BATCH * NHEAD * SEQ / 16), 256, 0, stream>>>(Q, Kt, Vt, O);
        gemm_bt64<<<dim3(D_MODEL / BN, ROWS / 64), 256, 0, stream>>>(
            O, owB + (size_t)l * D_MODEL * D_MODEL, out_b + (size_t)l * D_MODEL,
            Tb, ROWS, D_MODEL, D_MODEL, MODE_PLAIN);
        ln_residual<<<dim3(ROWS / 4), 256, 0, stream>>>(
            (l == 0) ? nullptr : xA, xf, Tb,
            ln1_s + (size_t)l * D_MODEL, ln1_b + (size_t)l * D_MODEL,
            xA, nullptr);
        gemm_bt128<<<dim3(D_FF / BN, ROWS / 128), 256, 0, stream>>>(
            xA, w1B + (size_t)l * D_FF * D_MODEL, b1 + (size_t)l * D_FF,
            Hb, nullptr, nullptr, nullptr, ROWS, D_FF, D_MODEL, MODE_RELU);
        gemm_bt64<<<dim3(D_MODEL / BN, ROWS / 64), 256, 0, stream>>>(
            Hb, w2B + (size_t)l * D_MODEL * D_FF, b2 + (size_t)l * D_MODEL,
            Tb, ROWS, D_MODEL, D_FF, MODE_PLAIN);
        if (l == NLAYERS - 1) {
            ln_residual<<<dim3(ROWS / 4), 256, 0, stream>>>(
                xA, nullptr, Tb, ln2_s + (size_t)l * D_MODEL, ln2_b + (size_t)l * D_MODEL,
                nullptr, out);
        } else {
            ln_residual<<<dim3(ROWS / 4), 256, 0, stream>>>(
                xA, nullptr, Tb, ln2_s + (size_t)l * D_MODEL, ln2_b + (size_t)l * D_MODEL,
                xA, nullptr);
        }
    }
}